// Round 10
// baseline (159.109 us; speedup 1.0000x reference)
//
#include <hip/hip_runtime.h>
#include <climits>

// FastNDCG via radix-partition with 4-byte records.
// Final record = loc(11 bits, user within 1563-slice) | i_local(20 bits,
// position within a 2^20-wide position-group). 8 groups x 256 slices buckets.
// Scatter temp record = s(8) | loc(11) | pos_in_chunk(12). Buckets are padded
// to multiples of 4 with sentinel records (loc=2047 -> trash table slot) so the
// reduce unpack loop is branch-free.
static constexpr int NUSERS = 400000;
static constexpr float NEG_INF_F = -1000000000.0f;
static constexpr float INV_LOG2_3 = 0.6309297535714575f; // 1/log2(3)

static constexpr int USLICE = 1563;                       // users/slice (256*1563 >= 400000)
static constexpr int S = 256;                             // user slices = CU count
static constexpr int TAB = 2048;                          // LDS table size (incl. trash slot)
static constexpr int CHUNK = 4096;                        // elems per scatter block
static constexpr int CPG = 256;                           // chunks per position-group
static constexpr int GSPAN = CHUNK * CPG;                 // 1048576 = 2^20
static constexpr int G = 8;                               // position groups
static constexpr int CAP = 4608;   // per-bucket cap (mean 4096, sigma ~64, +8σ)

// ---------------- partition path ----------------

__global__ __launch_bounds__(256, 8) void k_scatter(const int* __restrict__ idx, int n,
                                                    unsigned* __restrict__ records,
                                                    int* __restrict__ cursor) {
    __shared__ int cnt[S];           // 1 KB
    __shared__ int base_l[S + 1];    // 1 KB
    __shared__ int base_g[S];        // 1 KB
    __shared__ unsigned stage[CHUNK];// 16 KB

    const int t = threadIdx.x;
    const int g = blockIdx.x >> 8;            // blockIdx / CPG
    const int cbase = (blockIdx.x & (CPG - 1)) * CHUNK; // group-local pos base
    const int q0 = blockIdx.x * (CHUNK / 4);  // int4 base
    const int nq = n >> 2;                    // n divisible by 4
    const int4* idx4 = reinterpret_cast<const int4*>(idx);

    int4 v[4];
    int rnk[16];
#pragma unroll
    for (int k = 0; k < 4; ++k) {
        int q = q0 + k * 256 + t;
        v[k] = (q < nq) ? idx4[q] : make_int4(-1, -1, -1, -1);
    }

    if (t < S) cnt[t] = 0;
    __syncthreads();

    // Counting pass: the atomicAdd return value IS the rank (1 LDS atomic/record).
#pragma unroll
    for (int k = 0; k < 4; ++k) {
        int us[4] = {v[k].x, v[k].y, v[k].z, v[k].w};
#pragma unroll
        for (int e = 0; e < 4; ++e)
            rnk[k * 4 + e] = (us[e] >= 0) ? atomicAdd(&cnt[us[e] / USLICE], 1) : 0;
    }
    __syncthreads();

    // Wave-0 shuffle-based exclusive scan of cnt[0..255] (4 chunks of 64).
    if (t < 64) {
        int v0 = cnt[t];
        int v1 = cnt[64 + t];
        int v2 = cnt[128 + t];
        int v3 = cnt[192 + t];
        int a = v0, b = v1, c = v2, d = v3;
#pragma unroll
        for (int dd = 1; dd < 64; dd <<= 1) { int y = __shfl_up(a, dd, 64); if (t >= dd) a += y; }
        int ta = __shfl(a, 63, 64);
#pragma unroll
        for (int dd = 1; dd < 64; dd <<= 1) { int y = __shfl_up(b, dd, 64); if (t >= dd) b += y; }
        int tb = __shfl(b, 63, 64);
#pragma unroll
        for (int dd = 1; dd < 64; dd <<= 1) { int y = __shfl_up(c, dd, 64); if (t >= dd) c += y; }
        int tc = __shfl(c, 63, 64);
#pragma unroll
        for (int dd = 1; dd < 64; dd <<= 1) { int y = __shfl_up(d, dd, 64); if (t >= dd) d += y; }
        int td = __shfl(d, 63, 64);
        b += ta; c += ta + tb; d += ta + tb + tc;
        base_l[t] = a - v0;
        base_l[64 + t] = b - v1;
        base_l[128 + t] = c - v2;
        base_l[192 + t] = d - v3;
        if (t == 0) base_l[S] = ta + tb + tc + td;   // total
    }
    if (t < S) base_g[t] = atomicAdd(&cursor[g * S + t], cnt[t]);
    __syncthreads();

    // Stage bucket-sorted temp records in LDS: s(8)|loc(11)|pos_in_chunk(12).
#pragma unroll
    for (int k = 0; k < 4; ++k) {
        int us[4] = {v[k].x, v[k].y, v[k].z, v[k].w};
#pragma unroll
        for (int e = 0; e < 4; ++e) {
            int u = us[e];
            if (u >= 0) {
                int s = u / USLICE;
                int loc = u - s * USLICE;
                int pos = base_l[s] + rnk[k * 4 + e];
                unsigned pic = (unsigned)((k * 256 + t) * 4 + e);   // pos in chunk
                stage[pos] = ((unsigned)s << 23) | ((unsigned)loc << 12) | pic;
            }
        }
    }
    __syncthreads();

    // Coalesced-burst writeout (runs of ~16 records per bucket).
    int total = base_l[S];
    for (int r = t; r < total; r += 256) {
        unsigned tmp = stage[r];
        int s = tmp >> 23;
        unsigned loc = (tmp >> 12) & 0x7FFu;
        unsigned iloc = (unsigned)cbase + (tmp & 0xFFFu);
        int pos = base_g[s] + (r - base_l[s]);
        if (pos < CAP)  // never triggers for this data; memory-safety guard
            records[(size_t)(g * S + s) * CAP + pos] = (loc << 20) | iloc;
    }
    // Pad each bucket this block closed out to a multiple of 4 with sentinels
    // (loc=2047 -> trash slot, i=0). Only the block holding the tail pads.
    if (t < S) {
        int endp = base_g[t] + cnt[t];
        if (endp < CAP) {
            int endr = (endp + 3) & ~3;
            endr = min(endr, CAP);
            unsigned* bp = records + (size_t)(g * S + t) * CAP;
            for (int p = endp; p < endr; ++p) bp[p] = 0x7FF00000u;  // loc=2047, i=0
        }
    }
}

__global__ __launch_bounds__(1024, 4) void k_reduce_ndcg(
        const unsigned* __restrict__ records, const int* __restrict__ cursor,
        const float* __restrict__ pred, const float* __restrict__ tgt,
        int n, float* __restrict__ acc, unsigned* __restrict__ done,
        float* __restrict__ out) {
    __shared__ int tabf[TAB];   // 8 KB (slot 2047 = trash for pad records)
    __shared__ int tabl[TAB];   // 8 KB
    const int s = blockIdx.x;
    const int t = threadIdx.x;

    for (int u = t; u < TAB; u += 1024) { tabf[u] = INT_MAX; tabl[u] = -1; }
    __syncthreads();

    // Build the slice's complete first/last table from its 8 group-buckets.
    // Buckets are 4-padded with sentinels -> no per-element guard needed.
    for (int g = 0; g < G; ++g) {
        int cnt4 = (min(cursor[g * S + s], CAP) + 3) >> 2;
        const uint4* base4 = reinterpret_cast<const uint4*>(records + (size_t)(g * S + s) * CAP);
        const int gb = g * GSPAN;
        for (int p4 = t; p4 < cnt4; p4 += 1024) {
            uint4 vv = base4[p4];
            unsigned rr[4] = {vv.x, vv.y, vv.z, vv.w};
#pragma unroll
            for (int e = 0; e < 4; ++e) {
                int loc = rr[e] >> 20;
                int i = (int)(rr[e] & 0xFFFFFu) + gb;
                atomicMin(&tabf[loc], i);   // LDS atomics: CU-local
                atomicMax(&tabl[loc], i);
            }
        }
    }
    __syncthreads();

    // NDCG for this slice's users, straight from LDS.
    float v = 0.0f;
    for (int uu = t; uu < USLICE; uu += 1024) {
        int u = s * USLICE + uu;
        if (u < NUSERS) {
            int f = tabf[uu];
            int l = tabl[uu];
            f = min(f, n - 1);  // count==0: segment_min identity INT_MAX, jax clamps gather
            float p0 = pred[f];
            float t0 = tgt[f];
            bool has2 = l > f;  // count>=2 <=> distinct first/last positions
            float p1 = has2 ? pred[l] : NEG_INF_F;
            float t1 = has2 ? tgt[l] : 0.0f;
            float dcg  = (p0 >= p1) ? fmaf(t1, INV_LOG2_3, t0) : fmaf(t0, INV_LOG2_3, t1);
            float idcg = fmaf(fminf(t0, t1), INV_LOG2_3, fmaxf(t0, t1));
            v += dcg / idcg;    // 0/0 -> NaN matches reference
        }
    }
    for (int off = 32; off > 0; off >>= 1) v += __shfl_down(v, off, 64);
    __shared__ float wsum[16];
    int lane = t & 63, wid = t >> 6;
    if (lane == 0) wsum[wid] = v;
    __syncthreads();
    if (t == 0) {
        float ss = 0.0f;
#pragma unroll
        for (int w = 0; w < 16; ++w) ss += wsum[w];
        atomicAdd(acc, ss);
        __threadfence();                      // make acc add visible device-wide
        unsigned old = atomicAdd(done, 1u);   // device-scope completion count
        if (old == S - 1) {                   // last block finalizes
            __threadfence();
            out[0] = *((volatile float*)acc) * (1.0f / (float)NUSERS);
        }
    }
}

// ---------------- fallback path (R1, correct but slow) ----------------

__global__ void k_init_fb(int* __restrict__ first, int* __restrict__ last,
                          float* __restrict__ acc) {
    int i = blockIdx.x * blockDim.x + threadIdx.x;
    if (i < NUSERS) { first[i] = INT_MAX; last[i] = -1; }
    if (i == 0) acc[0] = 0.0f;
}

__global__ void k_minmax_fb(const int* __restrict__ idx, int* __restrict__ first,
                            int* __restrict__ last, int n) {
    int base = (blockIdx.x * blockDim.x + threadIdx.x) * 4;
    if (base + 3 < n) {
        int4 u4 = *reinterpret_cast<const int4*>(idx + base);
        int us[4] = {u4.x, u4.y, u4.z, u4.w};
#pragma unroll
        for (int j = 0; j < 4; ++j) {
            int u = us[j], i = base + j;
            if (i < first[u]) atomicMin(&first[u], i);
            if (i > last[u])  atomicMax(&last[u], i);
        }
    } else {
        for (int i = base; i < n; ++i) {
            int u = idx[i];
            if (i < first[u]) atomicMin(&first[u], i);
            if (i > last[u])  atomicMax(&last[u], i);
        }
    }
}

__global__ void k_ndcg_fb(const float* __restrict__ pred, const float* __restrict__ tgt,
                          const int* __restrict__ first, const int* __restrict__ last,
                          int n, float* __restrict__ acc) {
    int u = blockIdx.x * blockDim.x + threadIdx.x;
    float v = 0.0f;
    if (u < NUSERS) {
        int f = min(first[u], n - 1);
        int l = last[u];
        float p0 = pred[f], t0 = tgt[f];
        bool has2 = l > f;
        float p1 = has2 ? pred[l] : NEG_INF_F;
        float t1 = has2 ? tgt[l] : 0.0f;
        float dcg  = (p0 >= p1) ? fmaf(t1, INV_LOG2_3, t0) : fmaf(t0, INV_LOG2_3, t1);
        float idcg = fmaf(fminf(t0, t1), INV_LOG2_3, fmaxf(t0, t1));
        v = dcg / idcg;
    }
    for (int off = 32; off > 0; off >>= 1) v += __shfl_down(v, off, 64);
    __shared__ float wsum[4];
    int lane = threadIdx.x & 63, wid = threadIdx.x >> 6;
    if (lane == 0) wsum[wid] = v;
    __syncthreads();
    if (threadIdx.x == 0) atomicAdd(acc, wsum[0] + wsum[1] + wsum[2] + wsum[3]);
}

__global__ void k_final_fb(const float* __restrict__ acc, float* __restrict__ out) {
    out[0] = acc[0] * (1.0f / (float)NUSERS);
}

// ---------------- launch ----------------

extern "C" void kernel_launch(void* const* d_in, const int* in_sizes, int n_in,
                              void* d_out, int out_size, void* d_ws, size_t ws_size,
                              hipStream_t stream) {
    const float* pred = (const float*)d_in[0];
    const float* tgt  = (const float*)d_in[1];
    const int*   idx  = (const int*)d_in[2];
    const int n = in_sizes[0];
    float* out = (float*)d_out;

    const size_t recs_bytes = (size_t)G * S * CAP * sizeof(unsigned);   // ~37.7 MB
    const size_t need = recs_bytes + 16384;

    if (ws_size >= need && n <= G * GSPAN && (n & 3) == 0) {
        unsigned* records = (unsigned*)d_ws;
        char* tail = (char*)d_ws + recs_bytes;
        int* cursor = (int*)tail;                       // G*S ints = 8 KB
        float* acc = (float*)(tail + 8192);
        unsigned* done = (unsigned*)(tail + 8192 + 64);

        // Zero cursor + acc + done in one DMA fill (replaces the init kernel).
        hipMemsetAsync(tail, 0, 16384, stream);

        int nblocks = (n + CHUNK - 1) / CHUNK;
        k_scatter<<<nblocks, 256, 0, stream>>>(idx, n, records, cursor);

        k_reduce_ndcg<<<S, 1024, 0, stream>>>(records, cursor, pred, tgt, n,
                                              acc, done, out);
    } else {
        int* first = (int*)d_ws;
        int* last  = first + NUSERS;
        float* acc = (float*)(last + NUSERS);

        k_init_fb<<<(NUSERS + 255) / 256, 256, 0, stream>>>(first, last, acc);
        int nq4 = (n + 3) / 4;
        k_minmax_fb<<<(nq4 + 255) / 256, 256, 0, stream>>>(idx, first, last, n);
        k_ndcg_fb<<<(NUSERS + 255) / 256, 256, 0, stream>>>(pred, tgt, first, last, n, acc);
        k_final_fb<<<1, 1, 0, stream>>>(acc, out);
    }
}

// Round 11
// 156.032 us; speedup vs baseline: 1.0197x; 1.0197x over previous
//
#include <hip/hip_runtime.h>
#include <climits>

// FastNDCG via radix-partition with 4-byte records.  (R8 kernels + 3-dispatch launch)
// Final record = loc(11 bits, user within 1563-slice) | i_local(20 bits,
// position within a 1044480-wide position-group). 8 groups x 256 slices buckets.
// Scatter temp record = s(8) | loc(11) | pos_in_chunk(12) = 31 bits.
// Fused reduce+ndcg+final: one 1024-thread block per slice builds the complete
// first/last table in LDS, computes NDCG, and the last block writes the mean.
static constexpr int NUSERS = 400000;
static constexpr float NEG_INF_F = -1000000000.0f;
static constexpr float INV_LOG2_3 = 0.6309297535714575f; // 1/log2(3)

static constexpr int USLICE = 1563;                       // users/slice (256*1563 >= 400000)
static constexpr int S = 256;                             // user slices = CU count
static constexpr int CHUNK = 4096;                        // elems per scatter block
static constexpr int CPG = 255;                           // chunks per position-group
static constexpr int GSPAN = CHUNK * CPG;                 // 1044480 < 2^20
static constexpr int G = 8;                               // position groups
static constexpr int CAP = 4608;   // per-bucket cap (mean ~3906, sigma ~62, +11σ)

// ---------------- partition path ----------------

__global__ __launch_bounds__(256, 8) void k_scatter(const int* __restrict__ idx, int n,
                                                    unsigned* __restrict__ records,
                                                    int* __restrict__ cursor) {
    __shared__ int cnt[S];           // 1 KB
    __shared__ int base_l[S + 1];    // 1 KB
    __shared__ int base_g[S];        // 1 KB
    __shared__ unsigned stage[CHUNK];// 16 KB

    const int t = threadIdx.x;
    const int g = blockIdx.x / CPG;           // position group
    const int cbase = blockIdx.x * CHUNK - g * GSPAN; // chunk's group-local pos base
    const int q0 = blockIdx.x * (CHUNK / 4);  // int4 base
    const int nq = n >> 2;                    // n divisible by 4
    const int4* idx4 = reinterpret_cast<const int4*>(idx);

    int4 v[4];
    int rnk[16];
#pragma unroll
    for (int k = 0; k < 4; ++k) {
        int q = q0 + k * 256 + t;
        v[k] = (q < nq) ? idx4[q] : make_int4(-1, -1, -1, -1);
    }

    if (t < S) cnt[t] = 0;
    __syncthreads();

    // Counting pass: the atomicAdd return value IS the rank (1 LDS atomic/record).
#pragma unroll
    for (int k = 0; k < 4; ++k) {
        int us[4] = {v[k].x, v[k].y, v[k].z, v[k].w};
#pragma unroll
        for (int e = 0; e < 4; ++e)
            rnk[k * 4 + e] = (us[e] >= 0) ? atomicAdd(&cnt[us[e] / USLICE], 1) : 0;
    }
    __syncthreads();

    // Wave-0 shuffle-based exclusive scan of cnt[0..255] (4 chunks of 64).
    if (t < 64) {
        int v0 = cnt[t];
        int v1 = cnt[64 + t];
        int v2 = cnt[128 + t];
        int v3 = cnt[192 + t];
        int a = v0, b = v1, c = v2, d = v3;
#pragma unroll
        for (int dd = 1; dd < 64; dd <<= 1) { int y = __shfl_up(a, dd, 64); if (t >= dd) a += y; }
        int ta = __shfl(a, 63, 64);
#pragma unroll
        for (int dd = 1; dd < 64; dd <<= 1) { int y = __shfl_up(b, dd, 64); if (t >= dd) b += y; }
        int tb = __shfl(b, 63, 64);
#pragma unroll
        for (int dd = 1; dd < 64; dd <<= 1) { int y = __shfl_up(c, dd, 64); if (t >= dd) c += y; }
        int tc = __shfl(c, 63, 64);
#pragma unroll
        for (int dd = 1; dd < 64; dd <<= 1) { int y = __shfl_up(d, dd, 64); if (t >= dd) d += y; }
        int td = __shfl(d, 63, 64);
        b += ta; c += ta + tb; d += ta + tb + tc;
        base_l[t] = a - v0;
        base_l[64 + t] = b - v1;
        base_l[128 + t] = c - v2;
        base_l[192 + t] = d - v3;
        if (t == 0) base_l[S] = ta + tb + tc + td;   // total
    }
    if (t < S) base_g[t] = atomicAdd(&cursor[g * S + t], cnt[t]);
    __syncthreads();

    // Stage bucket-sorted temp records in LDS: s(8)|loc(11)|pos_in_chunk(12).
#pragma unroll
    for (int k = 0; k < 4; ++k) {
        int us[4] = {v[k].x, v[k].y, v[k].z, v[k].w};
#pragma unroll
        for (int e = 0; e < 4; ++e) {
            int u = us[e];
            if (u >= 0) {
                int s = u / USLICE;
                int loc = u - s * USLICE;
                int pos = base_l[s] + rnk[k * 4 + e];
                unsigned pic = (unsigned)((k * 256 + t) * 4 + e);   // pos in chunk
                stage[pos] = ((unsigned)s << 23) | ((unsigned)loc << 12) | pic;
            }
        }
    }
    __syncthreads();

    // Coalesced-burst writeout (runs of ~16 records per bucket).
    int total = base_l[S];
    for (int r = t; r < total; r += 256) {
        unsigned tmp = stage[r];
        int s = tmp >> 23;
        unsigned loc = (tmp >> 12) & 0x7FFu;
        unsigned iloc = (unsigned)cbase + (tmp & 0xFFFu);
        int pos = base_g[s] + (r - base_l[s]);
        if (pos < CAP)  // never triggers for this data; memory-safety guard
            records[(size_t)(g * S + s) * CAP + pos] = (loc << 20) | iloc;
    }
}

__global__ __launch_bounds__(1024, 4) void k_reduce_ndcg(
        const unsigned* __restrict__ records, const int* __restrict__ cursor,
        const float* __restrict__ pred, const float* __restrict__ tgt,
        int n, float* __restrict__ acc, unsigned* __restrict__ done,
        float* __restrict__ out) {
    __shared__ int tabf[USLICE];   // ~6.3 KB
    __shared__ int tabl[USLICE];   // ~6.3 KB
    const int s = blockIdx.x;
    const int t = threadIdx.x;

    for (int u = t; u < USLICE; u += 1024) { tabf[u] = INT_MAX; tabl[u] = -1; }
    __syncthreads();

    // Build the slice's complete first/last table from its 8 group-buckets.
    for (int g = 0; g < G; ++g) {
        int cnt = min(cursor[g * S + s], CAP);
        const uint4* base4 = reinterpret_cast<const uint4*>(records + (size_t)(g * S + s) * CAP);
        const int gb = g * GSPAN;
        for (int p4 = t; p4 * 4 < cnt; p4 += 1024) {
            uint4 vv = base4[p4];
            int p = p4 * 4;
            unsigned rr[4] = {vv.x, vv.y, vv.z, vv.w};
#pragma unroll
            for (int e = 0; e < 4; ++e) {
                if (p + e < cnt) {
                    int loc = rr[e] >> 20;
                    int i = (int)(rr[e] & 0xFFFFFu) + gb;
                    atomicMin(&tabf[loc], i);   // LDS atomics: CU-local
                    atomicMax(&tabl[loc], i);
                }
            }
        }
    }
    __syncthreads();

    // NDCG for this slice's users, straight from LDS.
    float v = 0.0f;
    for (int uu = t; uu < USLICE; uu += 1024) {
        int u = s * USLICE + uu;
        if (u < NUSERS) {
            int f = tabf[uu];
            int l = tabl[uu];
            f = min(f, n - 1);  // count==0: segment_min identity INT_MAX, jax clamps gather
            float p0 = pred[f];
            float t0 = tgt[f];
            bool has2 = l > f;  // count>=2 <=> distinct first/last positions
            float p1 = has2 ? pred[l] : NEG_INF_F;
            float t1 = has2 ? tgt[l] : 0.0f;
            float dcg  = (p0 >= p1) ? fmaf(t1, INV_LOG2_3, t0) : fmaf(t0, INV_LOG2_3, t1);
            float idcg = fmaf(fminf(t0, t1), INV_LOG2_3, fmaxf(t0, t1));
            v += dcg / idcg;    // 0/0 -> NaN matches reference
        }
    }
    for (int off = 32; off > 0; off >>= 1) v += __shfl_down(v, off, 64);
    __shared__ float wsum[16];
    int lane = t & 63, wid = t >> 6;
    if (lane == 0) wsum[wid] = v;
    __syncthreads();
    if (t == 0) {
        float ss = 0.0f;
#pragma unroll
        for (int w = 0; w < 16; ++w) ss += wsum[w];
        atomicAdd(acc, ss);
        __threadfence();                      // make acc add visible device-wide
        unsigned old = atomicAdd(done, 1u);   // device-scope completion count
        if (old == S - 1) {                   // last block finalizes
            __threadfence();
            out[0] = *((volatile float*)acc) * (1.0f / (float)NUSERS);
        }
    }
}

// ---------------- fallback path (R1, correct but slow) ----------------

__global__ void k_init_fb(int* __restrict__ first, int* __restrict__ last,
                          float* __restrict__ acc) {
    int i = blockIdx.x * blockDim.x + threadIdx.x;
    if (i < NUSERS) { first[i] = INT_MAX; last[i] = -1; }
    if (i == 0) acc[0] = 0.0f;
}

__global__ void k_minmax_fb(const int* __restrict__ idx, int* __restrict__ first,
                            int* __restrict__ last, int n) {
    int base = (blockIdx.x * blockDim.x + threadIdx.x) * 4;
    if (base + 3 < n) {
        int4 u4 = *reinterpret_cast<const int4*>(idx + base);
        int us[4] = {u4.x, u4.y, u4.z, u4.w};
#pragma unroll
        for (int j = 0; j < 4; ++j) {
            int u = us[j], i = base + j;
            if (i < first[u]) atomicMin(&first[u], i);
            if (i > last[u])  atomicMax(&last[u], i);
        }
    } else {
        for (int i = base; i < n; ++i) {
            int u = idx[i];
            if (i < first[u]) atomicMin(&first[u], i);
            if (i > last[u])  atomicMax(&last[u], i);
        }
    }
}

__global__ void k_ndcg_fb(const float* __restrict__ pred, const float* __restrict__ tgt,
                          const int* __restrict__ first, const int* __restrict__ last,
                          int n, float* __restrict__ acc) {
    int u = blockIdx.x * blockDim.x + threadIdx.x;
    float v = 0.0f;
    if (u < NUSERS) {
        int f = min(first[u], n - 1);
        int l = last[u];
        float p0 = pred[f], t0 = tgt[f];
        bool has2 = l > f;
        float p1 = has2 ? pred[l] : NEG_INF_F;
        float t1 = has2 ? tgt[l] : 0.0f;
        float dcg  = (p0 >= p1) ? fmaf(t1, INV_LOG2_3, t0) : fmaf(t0, INV_LOG2_3, t1);
        float idcg = fmaf(fminf(t0, t1), INV_LOG2_3, fmaxf(t0, t1));
        v = dcg / idcg;
    }
    for (int off = 32; off > 0; off >>= 1) v += __shfl_down(v, off, 64);
    __shared__ float wsum[4];
    int lane = threadIdx.x & 63, wid = threadIdx.x >> 6;
    if (lane == 0) wsum[wid] = v;
    __syncthreads();
    if (threadIdx.x == 0) atomicAdd(acc, wsum[0] + wsum[1] + wsum[2] + wsum[3]);
}

__global__ void k_final_fb(const float* __restrict__ acc, float* __restrict__ out) {
    out[0] = acc[0] * (1.0f / (float)NUSERS);
}

// ---------------- launch ----------------

extern "C" void kernel_launch(void* const* d_in, const int* in_sizes, int n_in,
                              void* d_out, int out_size, void* d_ws, size_t ws_size,
                              hipStream_t stream) {
    const float* pred = (const float*)d_in[0];
    const float* tgt  = (const float*)d_in[1];
    const int*   idx  = (const int*)d_in[2];
    const int n = in_sizes[0];
    float* out = (float*)d_out;

    const size_t recs_bytes = (size_t)G * S * CAP * sizeof(unsigned);   // ~37.7 MB
    const size_t need = recs_bytes + 16384;

    if (ws_size >= need && n <= G * GSPAN && (n & 3) == 0) {
        unsigned* records = (unsigned*)d_ws;
        char* tail = (char*)d_ws + recs_bytes;
        int* cursor = (int*)tail;                       // G*S ints = 8 KB
        float* acc = (float*)(tail + 8192);
        unsigned* done = (unsigned*)(tail + 8192 + 64);

        // Zero cursor + acc + done in one DMA fill (replaces the init kernel).
        hipMemsetAsync(tail, 0, 16384, stream);

        int nblocks = (n + CHUNK - 1) / CHUNK;
        k_scatter<<<nblocks, 256, 0, stream>>>(idx, n, records, cursor);

        k_reduce_ndcg<<<S, 1024, 0, stream>>>(records, cursor, pred, tgt, n,
                                              acc, done, out);
    } else {
        int* first = (int*)d_ws;
        int* last  = first + NUSERS;
        float* acc = (float*)(last + NUSERS);

        k_init_fb<<<(NUSERS + 255) / 256, 256, 0, stream>>>(first, last, acc);
        int nq4 = (n + 3) / 4;
        k_minmax_fb<<<(nq4 + 255) / 256, 256, 0, stream>>>(idx, first, last, n);
        k_ndcg_fb<<<(NUSERS + 255) / 256, 256, 0, stream>>>(pred, tgt, first, last, n, acc);
        k_final_fb<<<1, 1, 0, stream>>>(acc, out);
    }
}

// Round 12
// 150.644 us; speedup vs baseline: 1.0562x; 1.0358x over previous
//
#include <hip/hip_runtime.h>
#include <climits>

// FastNDCG via radix-partition with 4-byte records.   (exact R8 configuration —
// best measured: 150.9 us. R9/R10/R11 deviations all regressed; reverted.)
// Final record = loc(11 bits, user within 1563-slice) | i_local(20 bits,
// position within a 1044480-wide position-group). 8 groups x 256 slices buckets.
// Scatter temp record = s(8) | loc(11) | pos_in_chunk(12) = 31 bits.
// Fused reduce+ndcg: one 1024-thread block per slice builds the complete
// first/last table in LDS then computes NDCG directly (no partials).
static constexpr int NUSERS = 400000;
static constexpr float NEG_INF_F = -1000000000.0f;
static constexpr float INV_LOG2_3 = 0.6309297535714575f; // 1/log2(3)

static constexpr int USLICE = 1563;                       // users/slice (256*1563 >= 400000)
static constexpr int S = 256;                             // user slices = CU count
static constexpr int CHUNK = 4096;                        // elems per scatter block
static constexpr int CPG = 255;                           // chunks per position-group
static constexpr int GSPAN = CHUNK * CPG;                 // 1044480 < 2^20
static constexpr int G = 8;                               // position groups
static constexpr int CAP = 4608;   // per-bucket cap (mean ~3906, sigma ~62, +11σ)

// ---------------- partition path ----------------

__global__ void k_init_part(int* __restrict__ cursor, float* __restrict__ acc) {
    int t = blockIdx.x * blockDim.x + threadIdx.x;
    if (t < G * S) cursor[t] = 0;
    if (t == G * S) acc[0] = 0.0f;
}

__global__ __launch_bounds__(256, 8) void k_scatter(const int* __restrict__ idx, int n,
                                                    unsigned* __restrict__ records,
                                                    int* __restrict__ cursor) {
    __shared__ int cnt[S];           // 1 KB
    __shared__ int base_l[S + 1];    // 1 KB
    __shared__ int base_g[S];        // 1 KB
    __shared__ unsigned stage[CHUNK];// 16 KB

    const int t = threadIdx.x;
    const int g = blockIdx.x / CPG;           // position group
    const int cbase = blockIdx.x * CHUNK - g * GSPAN; // chunk's group-local pos base
    const int q0 = blockIdx.x * (CHUNK / 4);  // int4 base
    const int nq = n >> 2;                    // n divisible by 4
    const int4* idx4 = reinterpret_cast<const int4*>(idx);

    int4 v[4];
    int rnk[16];
#pragma unroll
    for (int k = 0; k < 4; ++k) {
        int q = q0 + k * 256 + t;
        v[k] = (q < nq) ? idx4[q] : make_int4(-1, -1, -1, -1);
    }

    if (t < S) cnt[t] = 0;
    __syncthreads();

    // Counting pass: the atomicAdd return value IS the rank (1 LDS atomic/record).
#pragma unroll
    for (int k = 0; k < 4; ++k) {
        int us[4] = {v[k].x, v[k].y, v[k].z, v[k].w};
#pragma unroll
        for (int e = 0; e < 4; ++e)
            rnk[k * 4 + e] = (us[e] >= 0) ? atomicAdd(&cnt[us[e] / USLICE], 1) : 0;
    }
    __syncthreads();

    // Wave-0 shuffle-based exclusive scan of cnt[0..255] (4 chunks of 64).
    if (t < 64) {
        int v0 = cnt[t];
        int v1 = cnt[64 + t];
        int v2 = cnt[128 + t];
        int v3 = cnt[192 + t];
        int a = v0, b = v1, c = v2, d = v3;
#pragma unroll
        for (int dd = 1; dd < 64; dd <<= 1) { int y = __shfl_up(a, dd, 64); if (t >= dd) a += y; }
        int ta = __shfl(a, 63, 64);
#pragma unroll
        for (int dd = 1; dd < 64; dd <<= 1) { int y = __shfl_up(b, dd, 64); if (t >= dd) b += y; }
        int tb = __shfl(b, 63, 64);
#pragma unroll
        for (int dd = 1; dd < 64; dd <<= 1) { int y = __shfl_up(c, dd, 64); if (t >= dd) c += y; }
        int tc = __shfl(c, 63, 64);
#pragma unroll
        for (int dd = 1; dd < 64; dd <<= 1) { int y = __shfl_up(d, dd, 64); if (t >= dd) d += y; }
        int td = __shfl(d, 63, 64);
        b += ta; c += ta + tb; d += ta + tb + tc;
        base_l[t] = a - v0;
        base_l[64 + t] = b - v1;
        base_l[128 + t] = c - v2;
        base_l[192 + t] = d - v3;
        if (t == 0) base_l[S] = ta + tb + tc + td;   // total
    }
    if (t < S) base_g[t] = atomicAdd(&cursor[g * S + t], cnt[t]);
    __syncthreads();

    // Stage bucket-sorted temp records in LDS: s(8)|loc(11)|pos_in_chunk(12).
#pragma unroll
    for (int k = 0; k < 4; ++k) {
        int us[4] = {v[k].x, v[k].y, v[k].z, v[k].w};
#pragma unroll
        for (int e = 0; e < 4; ++e) {
            int u = us[e];
            if (u >= 0) {
                int s = u / USLICE;
                int loc = u - s * USLICE;
                int pos = base_l[s] + rnk[k * 4 + e];
                unsigned pic = (unsigned)((k * 256 + t) * 4 + e);   // pos in chunk
                stage[pos] = ((unsigned)s << 23) | ((unsigned)loc << 12) | pic;
            }
        }
    }
    __syncthreads();

    // Coalesced-burst writeout (runs of ~16 records per bucket).
    int total = base_l[S];
    for (int r = t; r < total; r += 256) {
        unsigned tmp = stage[r];
        int s = tmp >> 23;
        unsigned loc = (tmp >> 12) & 0x7FFu;
        unsigned iloc = (unsigned)cbase + (tmp & 0xFFFu);
        int pos = base_g[s] + (r - base_l[s]);
        if (pos < CAP)  // never triggers for this data; memory-safety guard
            records[(size_t)(g * S + s) * CAP + pos] = (loc << 20) | iloc;
    }
}

__global__ __launch_bounds__(1024, 4) void k_reduce_ndcg(
        const unsigned* __restrict__ records, const int* __restrict__ cursor,
        const float* __restrict__ pred, const float* __restrict__ tgt,
        int n, float* __restrict__ acc) {
    __shared__ int tabf[USLICE];   // ~6.3 KB
    __shared__ int tabl[USLICE];   // ~6.3 KB
    const int s = blockIdx.x;
    const int t = threadIdx.x;

    for (int u = t; u < USLICE; u += 1024) { tabf[u] = INT_MAX; tabl[u] = -1; }
    __syncthreads();

    // Build the slice's complete first/last table from its 8 group-buckets.
    for (int g = 0; g < G; ++g) {
        int cnt = min(cursor[g * S + s], CAP);
        const uint4* base4 = reinterpret_cast<const uint4*>(records + (size_t)(g * S + s) * CAP);
        const int gb = g * GSPAN;
        for (int p4 = t; p4 * 4 < cnt; p4 += 1024) {
            uint4 vv = base4[p4];
            int p = p4 * 4;
            unsigned rr[4] = {vv.x, vv.y, vv.z, vv.w};
#pragma unroll
            for (int e = 0; e < 4; ++e) {
                if (p + e < cnt) {
                    int loc = rr[e] >> 20;
                    int i = (int)(rr[e] & 0xFFFFFu) + gb;
                    atomicMin(&tabf[loc], i);   // LDS atomics: CU-local
                    atomicMax(&tabl[loc], i);
                }
            }
        }
    }
    __syncthreads();

    // NDCG for this slice's users, straight from LDS.
    float v = 0.0f;
    for (int uu = t; uu < USLICE; uu += 1024) {
        int u = s * USLICE + uu;
        if (u < NUSERS) {
            int f = tabf[uu];
            int l = tabl[uu];
            f = min(f, n - 1);  // count==0: segment_min identity INT_MAX, jax clamps gather
            float p0 = pred[f];
            float t0 = tgt[f];
            bool has2 = l > f;  // count>=2 <=> distinct first/last positions
            float p1 = has2 ? pred[l] : NEG_INF_F;
            float t1 = has2 ? tgt[l] : 0.0f;
            float dcg  = (p0 >= p1) ? fmaf(t1, INV_LOG2_3, t0) : fmaf(t0, INV_LOG2_3, t1);
            float idcg = fmaf(fminf(t0, t1), INV_LOG2_3, fmaxf(t0, t1));
            v += dcg / idcg;    // 0/0 -> NaN matches reference
        }
    }
    for (int off = 32; off > 0; off >>= 1) v += __shfl_down(v, off, 64);
    __shared__ float wsum[16];
    int lane = t & 63, wid = t >> 6;
    if (lane == 0) wsum[wid] = v;
    __syncthreads();
    if (t == 0) {
        float ss = 0.0f;
#pragma unroll
        for (int w = 0; w < 16; ++w) ss += wsum[w];
        atomicAdd(acc, ss);
    }
}

__global__ void k_final(const float* __restrict__ acc, float* __restrict__ out) {
    out[0] = acc[0] * (1.0f / (float)NUSERS);
}

// ---------------- fallback path (R1, correct but slow) ----------------

__global__ void k_init_fb(int* __restrict__ first, int* __restrict__ last,
                          float* __restrict__ acc) {
    int i = blockIdx.x * blockDim.x + threadIdx.x;
    if (i < NUSERS) { first[i] = INT_MAX; last[i] = -1; }
    if (i == 0) acc[0] = 0.0f;
}

__global__ void k_minmax_fb(const int* __restrict__ idx, int* __restrict__ first,
                            int* __restrict__ last, int n) {
    int base = (blockIdx.x * blockDim.x + threadIdx.x) * 4;
    if (base + 3 < n) {
        int4 u4 = *reinterpret_cast<const int4*>(idx + base);
        int us[4] = {u4.x, u4.y, u4.z, u4.w};
#pragma unroll
        for (int j = 0; j < 4; ++j) {
            int u = us[j], i = base + j;
            if (i < first[u]) atomicMin(&first[u], i);
            if (i > last[u])  atomicMax(&last[u], i);
        }
    } else {
        for (int i = base; i < n; ++i) {
            int u = idx[i];
            if (i < first[u]) atomicMin(&first[u], i);
            if (i > last[u])  atomicMax(&last[u], i);
        }
    }
}

__global__ void k_ndcg_fb(const float* __restrict__ pred, const float* __restrict__ tgt,
                          const int* __restrict__ first, const int* __restrict__ last,
                          int n, float* __restrict__ acc) {
    int u = blockIdx.x * blockDim.x + threadIdx.x;
    float v = 0.0f;
    if (u < NUSERS) {
        int f = min(first[u], n - 1);
        int l = last[u];
        float p0 = pred[f], t0 = tgt[f];
        bool has2 = l > f;
        float p1 = has2 ? pred[l] : NEG_INF_F;
        float t1 = has2 ? tgt[l] : 0.0f;
        float dcg  = (p0 >= p1) ? fmaf(t1, INV_LOG2_3, t0) : fmaf(t0, INV_LOG2_3, t1);
        float idcg = fmaf(fminf(t0, t1), INV_LOG2_3, fmaxf(t0, t1));
        v = dcg / idcg;
    }
    for (int off = 32; off > 0; off >>= 1) v += __shfl_down(v, off, 64);
    __shared__ float wsum[4];
    int lane = threadIdx.x & 63, wid = threadIdx.x >> 6;
    if (lane == 0) wsum[wid] = v;
    __syncthreads();
    if (threadIdx.x == 0) atomicAdd(acc, wsum[0] + wsum[1] + wsum[2] + wsum[3]);
}

// ---------------- launch ----------------

extern "C" void kernel_launch(void* const* d_in, const int* in_sizes, int n_in,
                              void* d_out, int out_size, void* d_ws, size_t ws_size,
                              hipStream_t stream) {
    const float* pred = (const float*)d_in[0];
    const float* tgt  = (const float*)d_in[1];
    const int*   idx  = (const int*)d_in[2];
    const int n = in_sizes[0];
    float* out = (float*)d_out;

    const size_t recs_bytes = (size_t)G * S * CAP * sizeof(unsigned);   // ~37.7 MB
    const size_t need = recs_bytes + 16384;

    if (ws_size >= need && n <= G * GSPAN && (n & 3) == 0) {
        unsigned* records = (unsigned*)d_ws;
        char* tail = (char*)d_ws + recs_bytes;
        int* cursor = (int*)tail;                       // G*S ints = 8 KB
        float* acc = (float*)(tail + 8192);

        k_init_part<<<(G * S + 256) / 256, 256, 0, stream>>>(cursor, acc);

        int nblocks = (n + CHUNK - 1) / CHUNK;
        k_scatter<<<nblocks, 256, 0, stream>>>(idx, n, records, cursor);

        k_reduce_ndcg<<<S, 1024, 0, stream>>>(records, cursor, pred, tgt, n, acc);

        k_final<<<1, 1, 0, stream>>>(acc, out);
    } else {
        int* first = (int*)d_ws;
        int* last  = first + NUSERS;
        float* acc = (float*)(last + NUSERS);

        k_init_fb<<<(NUSERS + 255) / 256, 256, 0, stream>>>(first, last, acc);
        int nq4 = (n + 3) / 4;
        k_minmax_fb<<<(nq4 + 255) / 256, 256, 0, stream>>>(idx, first, last, n);
        k_ndcg_fb<<<(NUSERS + 255) / 256, 256, 0, stream>>>(pred, tgt, first, last, n, acc);
        k_final<<<1, 1, 0, stream>>>(acc, out);
    }
}